// Round 4
// baseline (1181.566 us; speedup 1.0000x reference)
//
#include <hip/hip_runtime.h>
#include <hip/hip_cooperative_groups.h>
#include <hip/hip_bf16.h>
#include <math.h>

namespace cg = cooperative_groups;

// Problem constants
#define LSEQ 2048
#define DMODEL 1024
#define DINNER 2048
#define DSTATE 16
#define DCONV 4
#define DTRANK 64
#define RPROJ 96   // DTRANK + 2*DSTATE

// Chunked-scan decomposition
#define CHUNK 32
#define NCHUNK (LSEQ / CHUNK)   // 64

#define XSPLIT 4                // split-K factor for x_proj
#define NBLK 512                // cooperative grid size (2 blocks/CU)

typedef __attribute__((ext_vector_type(8))) short bf16x8;
typedef __attribute__((ext_vector_type(4))) float f32x4;

__device__ __forceinline__ float softplusf(float x) {
    return (x > 20.f) ? x : log1pf(__expf(x));
}
__device__ __forceinline__ float siluf(float x) {
    return x / (1.f + __expf(-x));
}
// f32 -> bf16 RTNE
__device__ __forceinline__ short f2bf(float f) {
    union { float f; unsigned u; } v; v.f = f;
    unsigned r = v.u + 0x7FFFu + ((v.u >> 16) & 1u);
    return (short)(r >> 16);
}
// bf16 -> f32
__device__ __forceinline__ float bf2f(short h) {
    union { unsigned u; float f; } v;
    v.u = ((unsigned)(unsigned short)h) << 16;
    return v.f;
}

__device__ __forceinline__ void cvt8(const float* __restrict__ s,
                                     short* __restrict__ d, int i) {
    const float4 a = *(const float4*)(s + i);
    const float4 b = *(const float4*)(s + i + 4);
    alignas(16) short h[8];
    h[0] = f2bf(a.x); h[1] = f2bf(a.y); h[2] = f2bf(a.z); h[3] = f2bf(a.w);
    h[4] = f2bf(b.x); h[5] = f2bf(b.y); h[6] = f2bf(b.z); h[7] = f2bf(b.w);
    *(uint4*)(d + i) = *(const uint4*)h;
}

// ---------------- weight cvt phase (grid-stride) -------------------------
__device__ __forceinline__ void cvt_phase(
    const float* __restrict__ in_w, short* __restrict__ in_w_bf,
    const float* __restrict__ xp_w, short* __restrict__ xp_w_bf,
    const float* __restrict__ out_w, short* __restrict__ out_w_bf,
    const float* __restrict__ dtp_w, short* __restrict__ dtp_w_bf,
    int g0, int gstride)
{
    const int n1 = 2 * (2 * DINNER) * DMODEL;
    const int n2 = 2 * RPROJ * DINNER;
    const int n3 = 2 * DMODEL * DINNER;
    const int n4 = 2 * DINNER * DTRANK;
    const int total8 = (n1 + n2 + n3 + n4) / 8;
    for (int g = g0; g < total8; g += gstride) {
        int i = g * 8;
        if (i < n1) { cvt8(in_w, in_w_bf, i); continue; }
        i -= n1;
        if (i < n2) { cvt8(xp_w, xp_w_bf, i); continue; }
        i -= n2;
        if (i < n3) { cvt8(out_w, out_w_bf, i); continue; }
        i -= n3;
        cvt8(dtp_w, dtp_w_bf, i);
    }
}

// ---------------- LayerNorm phase: one wave per row ----------------------
__device__ __forceinline__ void ln_phase(
    const float* __restrict__ x, const float* __restrict__ w,
    const float* __restrict__ b, float* __restrict__ outf,
    short* __restrict__ outb, int bid, int tid)
{
    const int wv = tid >> 6, lane = tid & 63;
    const int row = bid * 4 + wv;
    const float* xr = x + (size_t)row * DMODEL;
    float v[16];
    float s = 0.f, sq = 0.f;
#pragma unroll
    for (int k = 0; k < 16; k++) {
        v[k] = xr[k * 64 + lane];
        s += v[k];
        sq += v[k] * v[k];
    }
#pragma unroll
    for (int off = 32; off > 0; off >>= 1) {
        s += __shfl_xor(s, off, 64);
        sq += __shfl_xor(sq, off, 64);
    }
    const float mu = s * (1.f / DMODEL);
    const float var = sq * (1.f / DMODEL) - mu * mu;
    const float rstd = rsqrtf(var + 1e-5f);
#pragma unroll
    for (int k = 0; k < 16; k++) {
        const int i = k * 64 + lane;
        const float o = (v[k] - mu) * rstd * w[i] + b[i];
        if (outf) outf[(size_t)row * DMODEL + i] = o;
        else      outb[(size_t)row * DMODEL + i] = f2bf(o);
    }
}

// ------ bf16 MFMA NT GEMM phase, (32*MI)x(32*NJ) tile, BK=64 -------------
// MODE 2: f32 (. + resid)   MODE 3: bf16 store   MODE 6: atomicAdd f32
template<int MI, int NJ, int MODE>
__device__ __forceinline__ void gemm_phase(
    unsigned char* smemraw,
    const short* __restrict__ A, int lda,
    const short* __restrict__ W, int ldw,
    float* __restrict__ Cf, short* __restrict__ Cb, int ldc,
    int N, int K, int row0, int col0, int kbeg,
    const float* __restrict__ resid, int tid)
{
    constexpr int BM = 32 * MI;
    constexpr int BN = 32 * NJ;
    constexpr int AISS = BM / 32;
    constexpr int WISS = BN / 32;
    short* As = (short*)smemraw;
    short* Ws = (short*)(smemraw + (size_t)BM * 64 * 2);

    const int lane = tid & 63;
    const int w = tid >> 6;
    const int wr = w >> 1, wc = w & 1;
    const int srow = tid >> 3;                       // 0..31
    const int dch  = tid & 7;                        // dest chunk 0..7
    const int skch = (dch ^ (srow & 7)) * 8;         // swizzled source col

    f32x4 acc[MI][NJ];
#pragma unroll
    for (int i = 0; i < MI; i++)
#pragma unroll
        for (int j = 0; j < NJ; j++) acc[i][j] = (f32x4)0.f;

    const int lrow = lane & 15;
    const int q = lane >> 4;

    for (int kt = kbeg; kt < kbeg + K; kt += 64) {
        __syncthreads();
#pragma unroll
        for (int j = 0; j < AISS; j++) {
            const short* gp = A + (size_t)(row0 + j * 32 + srow) * lda + kt + skch;
            __builtin_amdgcn_global_load_lds(
                (const __attribute__((address_space(1))) void*)gp,
                (__attribute__((address_space(3))) void*)(&As[j * 2048 + tid * 8]),
                16, 0, 0);
        }
#pragma unroll
        for (int j = 0; j < WISS; j++) {
            const int wrow = col0 + j * 32 + srow;
            if (wrow < N) {
                const short* gp = W + (size_t)wrow * ldw + kt + skch;
                __builtin_amdgcn_global_load_lds(
                    (const __attribute__((address_space(1))) void*)gp,
                    (__attribute__((address_space(3))) void*)(&Ws[j * 2048 + tid * 8]),
                    16, 0, 0);
            }
        }
        __syncthreads();

#pragma unroll
        for (int ks = 0; ks < 2; ks++) {
            bf16x8 af[MI], bfr[NJ];
#pragma unroll
            for (int i = 0; i < MI; i++) {
                const int R = wr * (16 * MI) + i * 16 + lrow;
                const int pc = (ks * 4 + q) ^ (R & 7);
                af[i] = *(const bf16x8*)&As[R * 64 + pc * 8];
            }
#pragma unroll
            for (int j = 0; j < NJ; j++) {
                const int R = wc * (16 * NJ) + j * 16 + lrow;
                const int pc = (ks * 4 + q) ^ (R & 7);
                bfr[j] = *(const bf16x8*)&Ws[R * 64 + pc * 8];
            }
#pragma unroll
            for (int i = 0; i < MI; i++)
#pragma unroll
                for (int j = 0; j < NJ; j++)
                    acc[i][j] = __builtin_amdgcn_mfma_f32_16x16x32_bf16(
                        af[i], bfr[j], acc[i][j], 0, 0, 0);
        }
    }

    // epilogue: C/D layout col=lane&15, row=(lane>>4)*4+reg
    const int rbase = row0 + wr * (16 * MI);
    const int cbase = col0 + wc * (16 * NJ);
#pragma unroll
    for (int i = 0; i < MI; i++) {
#pragma unroll
        for (int j = 0; j < NJ; j++) {
            const int gcol = cbase + j * 16 + lrow;
            if (gcol < N) {
#pragma unroll
                for (int r = 0; r < 4; r++) {
                    const int grow = rbase + i * 16 + (lane >> 4) * 4 + r;
                    float v = acc[i][j][r];
                    if (MODE == 2) {
                        Cf[(size_t)grow * ldc + gcol] =
                            v + resid[(size_t)grow * ldc + gcol];
                    } else if (MODE == 3) {
                        Cb[(size_t)grow * ldc + gcol] = f2bf(v);
                    } else {  // MODE 6: split-K accumulate
                        atomicAdd(&Cf[(size_t)grow * ldc + gcol], v);
                    }
                }
            }
        }
    }
}

// ---------- dt_proj phase: 64x128 tile, K=64 -----------------------------
__device__ __forceinline__ void dtproj_phase(
    unsigned char* smemraw,
    const float* __restrict__ dbl,      // [L,RPROJ] f32 (cols 0..63 used)
    const short* __restrict__ dtp_w,    // [DINNER,64] bf16
    const float* __restrict__ dtp_b,    // [DINNER]
    short* __restrict__ dt_bf,          // [L,DINNER]
    int row0, int col0, int tid)
{
    short* As = (short*)smemraw;                  // 64*32 shorts = 4KB
    short* Ws = (short*)(smemraw + 64 * 32 * 2);  // 128*32 shorts = 8KB
    const int lane = tid & 63;
    const int w = tid >> 6;
    const int wr = w >> 1, wc = w & 1;
    const int srow = tid >> 2;
    const int skch = ((tid & 3) ^ ((srow >> 1) & 3)) * 8;
    const int lrow = lane & 15;
    const int q = lane >> 4;

    f32x4 acc[2][4];
#pragma unroll
    for (int i = 0; i < 2; i++)
#pragma unroll
        for (int j = 0; j < 4; j++) acc[i][j] = (f32x4)0.f;

#pragma unroll
    for (int kt = 0; kt < 64; kt += 32) {
        __syncthreads();
        {
            const float* gp = dbl + (size_t)(row0 + srow) * RPROJ + kt + skch;
            const float4 a = *(const float4*)gp;
            const float4 b = *(const float4*)(gp + 4);
            alignas(16) short h[8];
            h[0] = f2bf(a.x); h[1] = f2bf(a.y); h[2] = f2bf(a.z); h[3] = f2bf(a.w);
            h[4] = f2bf(b.x); h[5] = f2bf(b.y); h[6] = f2bf(b.z); h[7] = f2bf(b.w);
            *(uint4*)(As + tid * 8) = *(const uint4*)h;
        }
#pragma unroll
        for (int j = 0; j < 2; j++) {
            const short* gp = dtp_w + (size_t)(col0 + j * 64 + srow) * DTRANK + kt + skch;
            __builtin_amdgcn_global_load_lds(
                (const __attribute__((address_space(1))) void*)gp,
                (__attribute__((address_space(3))) void*)(&Ws[j * 2048 + tid * 8]),
                16, 0, 0);
        }
        __syncthreads();

        bf16x8 af[2], bfr[4];
#pragma unroll
        for (int i = 0; i < 2; i++) {
            const int R = wr * 32 + i * 16 + lrow;
            af[i] = *(const bf16x8*)&As[R * 32 + ((q ^ ((R >> 1) & 3)) * 8)];
        }
#pragma unroll
        for (int j = 0; j < 4; j++) {
            const int R = wc * 64 + j * 16 + lrow;
            bfr[j] = *(const bf16x8*)&Ws[R * 32 + ((q ^ ((R >> 1) & 3)) * 8)];
        }
#pragma unroll
        for (int i = 0; i < 2; i++)
#pragma unroll
            for (int j = 0; j < 4; j++)
                acc[i][j] = __builtin_amdgcn_mfma_f32_16x16x32_bf16(
                    af[i], bfr[j], acc[i][j], 0, 0, 0);
    }

    const int rbase = row0 + wr * 32;
    const int cbase = col0 + wc * 64;
#pragma unroll
    for (int i = 0; i < 2; i++)
#pragma unroll
        for (int j = 0; j < 4; j++) {
            const int gcol = cbase + j * 16 + lrow;
#pragma unroll
            for (int r = 0; r < 4; r++) {
                const int grow = rbase + i * 16 + (lane >> 4) * 4 + r;
                dt_bf[(size_t)grow * DINNER + gcol] =
                    f2bf(softplusf(acc[i][j][r] + dtp_b[gcol]));
            }
        }
}

// ---------------- conv + silu phase (grid-stride) ------------------------
__device__ __forceinline__ void conv_phase(
    const short* __restrict__ xzb, const float* __restrict__ cw,
    const float* __restrict__ cb, short* __restrict__ xcb,
    float* __restrict__ dbl_zero, int gid0, int gstride)
{
    for (int g = gid0; g < (LSEQ * DINNER) / 8; g += gstride) {
        if (g < (LSEQ * RPROJ) / 4)
            *(float4*)(dbl_zero + g * 4) = make_float4(0.f, 0.f, 0.f, 0.f);
        const int t = g >> 8;
        const int c0 = (g & 255) * 8;
        float acc[8];
#pragma unroll
        for (int j = 0; j < 8; j++) acc[j] = cb[c0 + j];
#pragma unroll
        for (int k = 0; k < DCONV; k++) {
            const int tt = t - (DCONV - 1) + k;
            if (tt >= 0) {
                const bf16x8 v = *(const bf16x8*)(xzb + (size_t)tt * (2 * DINNER) + c0);
#pragma unroll
                for (int j = 0; j < 8; j++)
                    acc[j] += bf2f(v[j]) * cw[(c0 + j) * DCONV + k];
            }
        }
        alignas(16) short h[8];
#pragma unroll
        for (int j = 0; j < 8; j++) h[j] = f2bf(siluf(acc[j]));
        *(uint4*)(xcb + (size_t)t * DINNER + c0) = *(const uint4*)h;
    }
}

// ---------------- scan phases (CHUNK=32) ---------------------------------
__device__ __forceinline__ void scan1_job(
    int eb, int c, int tid, float* sBC,
    const short* __restrict__ dtb, const short* __restrict__ xcb,
    const float* __restrict__ dbl, const float* __restrict__ A_log,
    float* __restrict__ S, float* __restrict__ sumdt)
{
    const int e = eb * 256 + tid;
    float a[DSTATE];
#pragma unroll
    for (int n = 0; n < DSTATE; n++) a[n] = -__expf(A_log[(size_t)e * DSTATE + n]);
    float h[DSTATE];
#pragma unroll
    for (int n = 0; n < DSTATE; n++) h[n] = 0.f;
    float sd = 0.f;

    __syncthreads();   // guard prior sBC use
    for (int i = tid; i < CHUNK * 32; i += 256) {
        const int tl = i >> 5, j = i & 31;
        sBC[tl * 32 + j] = dbl[(size_t)(c * CHUNK + tl) * RPROJ + DTRANK + j];
    }
    __syncthreads();

    const size_t rb = (size_t)c * CHUNK * DINNER + e;
    short dt_c = dtb[rb], xc_c = xcb[rb];
#pragma unroll 4
    for (int tl = 0; tl < CHUNK; tl++) {
        short dt_n = 0, xc_n = 0;
        if (tl + 1 < CHUNK) {
            dt_n = dtb[rb + (size_t)(tl + 1) * DINNER];
            xc_n = xcb[rb + (size_t)(tl + 1) * DINNER];
        }
        const float dtv = bf2f(dt_c);
        const float du = dtv * bf2f(xc_c);
        sd += dtv;
#pragma unroll
        for (int n = 0; n < DSTATE; n++) {
            const float dA = __expf(dtv * a[n]);
            h[n] = dA * h[n] + du * sBC[tl * 32 + n];
        }
        dt_c = dt_n; xc_c = xc_n;
    }
    sumdt[(size_t)c * DINNER + e] = sd;
#pragma unroll
    for (int n = 0; n < DSTATE; n++)
        S[((size_t)c * DSTATE + n) * DINNER + e] = h[n];
}

__device__ __forceinline__ void scan2_phase(
    const float* __restrict__ A_log, const float* __restrict__ sumdt,
    float* __restrict__ S, int idx)
{
    const int e = idx & (DINNER - 1);
    const int n = idx >> 11;
    const float a = -__expf(A_log[(size_t)e * DSTATE + n]);
    const size_t base = (size_t)n * DINNER + e;
    const size_t cstr = (size_t)DSTATE * DINNER;
    float H = 0.f;
    for (int c = 0; c < NCHUNK; c += 4) {
        const float sc0 = S[base + (size_t)(c + 0) * cstr];
        const float sc1 = S[base + (size_t)(c + 1) * cstr];
        const float sc2 = S[base + (size_t)(c + 2) * cstr];
        const float sc3 = S[base + (size_t)(c + 3) * cstr];
        const float sd0 = sumdt[(size_t)(c + 0) * DINNER + e];
        const float sd1 = sumdt[(size_t)(c + 1) * DINNER + e];
        const float sd2 = sumdt[(size_t)(c + 2) * DINNER + e];
        const float sd3 = sumdt[(size_t)(c + 3) * DINNER + e];
        S[base + (size_t)(c + 0) * cstr] = H;
        H = __expf(a * sd0) * H + sc0;
        S[base + (size_t)(c + 1) * cstr] = H;
        H = __expf(a * sd1) * H + sc1;
        S[base + (size_t)(c + 2) * cstr] = H;
        H = __expf(a * sd2) * H + sc2;
        S[base + (size_t)(c + 3) * cstr] = H;
        H = __expf(a * sd3) * H + sc3;
    }
}

__device__ __forceinline__ void scan3_job(
    int eb, int c, int tid, float* sBC,
    const short* __restrict__ dtb, const short* __restrict__ xcb,
    const float* __restrict__ dbl, const short* __restrict__ xzb,
    const float* __restrict__ A_log, const float* __restrict__ Dp,
    const float* __restrict__ S, short* __restrict__ yb)
{
    const int e = eb * 256 + tid;
    float a[DSTATE];
#pragma unroll
    for (int n = 0; n < DSTATE; n++) a[n] = -__expf(A_log[(size_t)e * DSTATE + n]);
    float h[DSTATE];
#pragma unroll
    for (int n = 0; n < DSTATE; n++)
        h[n] = S[((size_t)c * DSTATE + n) * DINNER + e];
    const float dskip = Dp[e];

    __syncthreads();   // guard prior sBC use
    for (int i = tid; i < CHUNK * 32; i += 256) {
        const int tl = i >> 5, j = i & 31;
        sBC[tl * 32 + j] = dbl[(size_t)(c * CHUNK + tl) * RPROJ + DTRANK + j];
    }
    __syncthreads();

    const size_t rb = (size_t)c * CHUNK * DINNER + e;
    const size_t zb = (size_t)c * CHUNK * (2 * DINNER) + DINNER + e;
    short dt_c = dtb[rb], xc_c = xcb[rb], z_c = xzb[zb];
#pragma unroll 4
    for (int tl = 0; tl < CHUNK; tl++) {
        short dt_n = 0, xc_n = 0, z_n = 0;
        if (tl + 1 < CHUNK) {
            dt_n = dtb[rb + (size_t)(tl + 1) * DINNER];
            xc_n = xcb[rb + (size_t)(tl + 1) * DINNER];
            z_n = xzb[zb + (size_t)(tl + 1) * (2 * DINNER)];
        }
        const float dtv = bf2f(dt_c);
        const float xcv = bf2f(xc_c);
        const float du = dtv * xcv;
        float yv = 0.f;
#pragma unroll
        for (int n = 0; n < DSTATE; n++) {
            const float dA = __expf(dtv * a[n]);
            h[n] = dA * h[n] + du * sBC[tl * 32 + n];
            yv += h[n] * sBC[tl * 32 + 16 + n];
        }
        yv = (yv + xcv * dskip) * siluf(bf2f(z_c));
        yb[rb + (size_t)tl * DINNER] = f2bf(yv);
        dt_c = dt_n; xc_c = xc_n; z_c = z_n;
    }
}

// =========================== param pack ==================================
struct MegaParams {
    const float *x_in, *ln_w, *ln_b, *in_w, *conv_w, *conv_b, *xp_w, *dtp_w,
                *dtp_b, *A_log, *D_skip, *out_w, *nf_w, *nf_b;
    float* out;
    float *buf_x, *dbl, *Sbuf, *sumdt;
    short *h_bf, *xz_bf, *xc_bf, *dt_bf, *y_bf;
    short *in_w_bf, *xp_w_bf, *dtp_w_bf, *out_w_bf;
};

// ============ Group A: LN -> in_proj -> conv (2 grid syncs) ==============
__global__ __launch_bounds__(256, 2) void groupA_kernel(MegaParams p, int layer)
{
    cg::grid_group grid = cg::this_grid();
    __shared__ alignas(16) unsigned char smem[32768];
    const int bid = blockIdx.x;
    const int tid = threadIdx.x;
    const float* resid = layer ? p.buf_x : p.x_in;

    ln_phase(resid, p.ln_w + layer * DMODEL, p.ln_b + layer * DMODEL,
             nullptr, p.h_bf, bid, tid);
    grid.sync();
    {
        const int swz = (bid & 7) * 64 + (bid >> 3);   // 512 = 8*64, bijective
        const int tx = swz & 31, ty = swz >> 5;        // 32 x 16
        gemm_phase<4, 4, 3>(smem,
            p.h_bf, DMODEL,
            p.in_w_bf + (size_t)layer * 2 * DINNER * DMODEL, DMODEL,
            nullptr, p.xz_bf, 2 * DINNER,
            2 * DINNER, DMODEL, ty * 128, tx * 128, 0, nullptr, tid);
    }
    grid.sync();
    conv_phase(p.xz_bf, p.conv_w + (size_t)layer * DINNER * DCONV,
               p.conv_b + layer * DINNER, p.xc_bf, p.dbl,
               bid * 256 + tid, NBLK * 256);
}

// == Group B: x_proj -> dt_proj -> scan1 -> scan2 -> scan3 (4 grid syncs) =
__global__ __launch_bounds__(256, 2) void groupB_kernel(MegaParams p, int layer)
{
    cg::grid_group grid = cg::this_grid();
    __shared__ alignas(16) unsigned char smem[16384];
    const int bid = blockIdx.x;
    const int tid = threadIdx.x;
    const float* Al = p.A_log + (size_t)layer * DINNER * DSTATE;

    if (bid < 2 * 32 * XSPLIT) {
        const int jx = bid & 1, jy = (bid >> 1) & 31, jz = bid >> 6;
        gemm_phase<2, 2, 6>(smem,
            p.xc_bf, DINNER,
            p.xp_w_bf + (size_t)layer * RPROJ * DINNER, DINNER,
            p.dbl, nullptr, RPROJ,
            RPROJ, DINNER / XSPLIT, jy * 64, jx * 64,
            jz * (DINNER / XSPLIT), nullptr, tid);
    }
    grid.sync();
    {
        const int jx = bid & 15, jy = bid >> 4;
        dtproj_phase(smem, p.dbl,
                     p.dtp_w_bf + (size_t)layer * DINNER * DTRANK,
                     p.dtp_b + layer * DINNER, p.dt_bf,
                     jy * 64, jx * 128, tid);
    }
    grid.sync();
    scan1_job(bid & 7, bid >> 3, tid, (float*)smem,
              p.dt_bf, p.xc_bf, p.dbl, Al, p.Sbuf, p.sumdt);
    grid.sync();
    if (bid < (DINNER * DSTATE) / 256)
        scan2_phase(Al, p.sumdt, p.Sbuf, bid * 256 + tid);
    grid.sync();
    scan3_job(bid & 7, bid >> 3, tid, (float*)smem,
              p.dt_bf, p.xc_bf, p.dbl, p.xz_bf, Al,
              p.D_skip + layer * DINNER, p.Sbuf, p.y_bf);
}

// ================== plain __global__ wrappers ============================
__global__ __launch_bounds__(256) void cvt_g(
    const float* in_w, short* in_w_bf, const float* xp_w, short* xp_w_bf,
    const float* out_w, short* out_w_bf, const float* dtp_w, short* dtp_w_bf)
{
    cvt_phase(in_w, in_w_bf, xp_w, xp_w_bf, out_w, out_w_bf, dtp_w, dtp_w_bf,
              blockIdx.x * 256 + threadIdx.x, gridDim.x * 256);
}

__global__ __launch_bounds__(256) void ln_g(
    const float* x, const float* w, const float* b, float* outf, short* outb)
{
    ln_phase(x, w, b, outf, outb, blockIdx.x, threadIdx.x);
}

template<int MI, int NJ, int MODE>
__global__ __launch_bounds__(256) void gemm_g(
    const short* A, int lda, const short* W, int ldw,
    float* Cf, short* Cb, int ldc, int N, int K, const float* resid)
{
    __shared__ alignas(16) unsigned char smem[(32 * MI + 32 * NJ) * 64 * 2];
    gemm_phase<MI, NJ, MODE>(smem, A, lda, W, ldw, Cf, Cb, ldc, N, K,
                             blockIdx.y * 32 * MI, blockIdx.x * 32 * NJ,
                             blockIdx.z * K, resid, threadIdx.x);
}

__global__ __launch_bounds__(256) void conv_g(
    const short* xzb, const float* cw, const float* cb, short* xcb,
    float* dbl_zero)
{
    conv_phase(xzb, cw, cb, xcb, dbl_zero,
               blockIdx.x * 256 + threadIdx.x, gridDim.x * 256);
}

__global__ __launch_bounds__(256) void dtproj_g(
    const float* dbl, const short* dtp_w, const float* dtp_b, short* dt_bf)
{
    __shared__ alignas(16) unsigned char smem[(64 + 128) * 32 * 2];
    dtproj_phase(smem, dbl, dtp_w, dtp_b, dt_bf,
                 blockIdx.y * 64, blockIdx.x * 128, threadIdx.x);
}

__global__ __launch_bounds__(256) void scan1_g(
    const short* dtb, const short* xcb, const float* dbl,
    const float* A_log, float* S, float* sumdt)
{
    __shared__ float sBC[CHUNK * 32];
    scan1_job(blockIdx.x, blockIdx.y, threadIdx.x, sBC,
              dtb, xcb, dbl, A_log, S, sumdt);
}

__global__ __launch_bounds__(256) void scan2_g(
    const float* A_log, const float* sumdt, float* S)
{
    scan2_phase(A_log, sumdt, S, blockIdx.x * 256 + threadIdx.x);
}

__global__ __launch_bounds__(256) void scan3_g(
    const short* dtb, const short* xcb, const float* dbl, const short* xzb,
    const float* A_log, const float* Dp, const float* S, short* yb)
{
    __shared__ float sBC[CHUNK * 32];
    scan3_job(blockIdx.x, blockIdx.y, threadIdx.x, sBC,
              dtb, xcb, dbl, xzb, A_log, Dp, S, yb);
}

extern "C" void kernel_launch(void* const* d_in, const int* in_sizes, int n_in,
                              void* d_out, int out_size, void* d_ws, size_t ws_size,
                              hipStream_t stream) {
    float* w = (float*)d_ws;
    float* buf_x = w; w += (size_t)LSEQ * DMODEL;              // residual stream (f32)
    float* dbl   = w; w += (size_t)LSEQ * RPROJ;               // x_proj out (f32)
    float* Sbuf  = w; w += (size_t)NCHUNK * DSTATE * DINNER;   // chunk summaries
    float* sumdt = w; w += (size_t)NCHUNK * DINNER;
    // bf16 buffers (sized in float units, 2 shorts per float)
    short* h_bf    = (short*)w; w += (size_t)LSEQ * DMODEL / 2;
    short* xz_bf   = (short*)w; w += (size_t)LSEQ * 2 * DINNER / 2;
    short* xc_bf   = (short*)w; w += (size_t)LSEQ * DINNER / 2;
    short* dt_bf   = (short*)w; w += (size_t)LSEQ * DINNER / 2;
    short* y_bf    = (short*)w; w += (size_t)LSEQ * DINNER / 2;
    short* in_w_bf  = (short*)w; w += (size_t)2 * (2 * DINNER) * DMODEL / 2;
    short* xp_w_bf  = (short*)w; w += (size_t)2 * RPROJ * DINNER / 2;
    short* dtp_w_bf = (short*)w; w += (size_t)2 * DINNER * DTRANK / 2;
    short* out_w_bf = (short*)w; w += (size_t)2 * DMODEL * DINNER / 2;

    MegaParams p;
    p.x_in   = (const float*)d_in[0];
    p.ln_w   = (const float*)d_in[1];
    p.ln_b   = (const float*)d_in[2];
    p.in_w   = (const float*)d_in[3];
    p.conv_w = (const float*)d_in[4];
    p.conv_b = (const float*)d_in[5];
    p.xp_w   = (const float*)d_in[6];
    p.dtp_w  = (const float*)d_in[7];
    p.dtp_b  = (const float*)d_in[8];
    p.A_log  = (const float*)d_in[9];
    p.D_skip = (const float*)d_in[10];
    p.out_w  = (const float*)d_in[11];
    p.nf_w   = (const float*)d_in[12];
    p.nf_b   = (const float*)d_in[13];
    p.out    = (float*)d_out;
    p.buf_x = buf_x; p.dbl = dbl; p.Sbuf = Sbuf; p.sumdt = sumdt;
    p.h_bf = h_bf; p.xz_bf = xz_bf; p.xc_bf = xc_bf; p.dt_bf = dt_bf;
    p.y_bf = y_bf;
    p.in_w_bf = in_w_bf; p.xp_w_bf = xp_w_bf; p.dtp_w_bf = dtp_w_bf;
    p.out_w_bf = out_w_bf;

    // ---- cooperative-launch gate: occupancy pre-check + cached result ----
    static int coop_state = -1;   // -1 unknown, 0 disabled, 1 enabled
    if (coop_state == -1) {
        int dev = 0;
        (void)hipGetDevice(&dev);
        hipDeviceProp_t prop;
        int na = 0, nb = 0;
        if (hipGetDeviceProperties(&prop, dev) == hipSuccess &&
            hipOccupancyMaxActiveBlocksPerMultiprocessor(
                &na, (const void*)groupA_kernel, 256, 0) == hipSuccess &&
            hipOccupancyMaxActiveBlocksPerMultiprocessor(
                &nb, (const void*)groupB_kernel, 256, 0) == hipSuccess &&
            na * prop.multiProcessorCount >= NBLK &&
            nb * prop.multiProcessorCount >= NBLK) {
            coop_state = 1;
        } else {
            coop_state = 0;
        }
    }

    bool ok = (coop_state == 1);
    if (ok) {
        cvt_g<<<dim3(6464), dim3(256), 0, stream>>>(
            p.in_w, in_w_bf, p.xp_w, xp_w_bf, p.out_w, out_w_bf,
            p.dtp_w, dtp_w_bf);
        for (int layer = 0; layer < 2 && ok; layer++) {
            int lyr = layer;
            void* args[] = { &p, &lyr };
            if (hipLaunchCooperativeKernel((void*)groupA_kernel, dim3(NBLK),
                                           dim3(256), args, 0, stream)
                != hipSuccess) { ok = false; break; }
            if (hipLaunchCooperativeKernel((void*)groupB_kernel, dim3(NBLK),
                                           dim3(256), args, 0, stream)
                != hipSuccess) { ok = false; break; }
            const float* resid_src = (layer == 0) ? p.x_in : buf_x;
            gemm_g<2, 2, 2><<<dim3(16, 32), dim3(256), 0, stream>>>(
                y_bf, DINNER, out_w_bf + (size_t)layer * DMODEL * DINNER,
                DINNER, buf_x, nullptr, DMODEL, DMODEL, DINNER, resid_src);
        }
        if (ok) {
            ln_g<<<dim3(NBLK), dim3(256), 0, stream>>>(
                buf_x, p.nf_w, p.nf_b, (float*)d_out, nullptr);
            return;
        }
        (void)hipGetLastError();  // clear; fall through to safe path
        coop_state = 0;
    }

    // ---- fallback: verified multi-dispatch path (same phase functions) ----
    cvt_g<<<dim3(6464), dim3(256), 0, stream>>>(
        p.in_w, in_w_bf, p.xp_w, xp_w_bf, p.out_w, out_w_bf, p.dtp_w, dtp_w_bf);
    for (int layer = 0; layer < 2; layer++) {
        const float* resid_src = (layer == 0) ? p.x_in : buf_x;
        ln_g<<<dim3(NBLK), dim3(256), 0, stream>>>(
            resid_src, p.ln_w + layer * DMODEL, p.ln_b + layer * DMODEL,
            nullptr, h_bf);
        gemm_g<4, 4, 3><<<dim3(32, 16), dim3(256), 0, stream>>>(
            h_bf, DMODEL, in_w_bf + (size_t)layer * 2 * DINNER * DMODEL, DMODEL,
            nullptr, xz_bf, 2 * DINNER, 2 * DINNER, DMODEL, nullptr);
        conv_g<<<dim3(2048), dim3(256), 0, stream>>>(
            xz_bf, p.conv_w + (size_t)layer * DINNER * DCONV,
            p.conv_b + layer * DINNER, xc_bf, dbl);
        gemm_g<2, 2, 6><<<dim3(2, 32, XSPLIT), dim3(256), 0, stream>>>(
            xc_bf, DINNER, xp_w_bf + (size_t)layer * RPROJ * DINNER, DINNER,
            dbl, nullptr, RPROJ, RPROJ, DINNER / XSPLIT, nullptr);
        dtproj_g<<<dim3(16, 32), dim3(256), 0, stream>>>(
            dbl, dtp_w_bf + (size_t)layer * DINNER * DTRANK,
            p.dtp_b + layer * DINNER, dt_bf);
        const float* Al = p.A_log + (size_t)layer * DINNER * DSTATE;
        scan1_g<<<dim3(8, NCHUNK), dim3(256), 0, stream>>>(
            dt_bf, xc_bf, dbl, Al, Sbuf, sumdt);
        scan2_g<<<dim3((DINNER * DSTATE) / 256), dim3(256), 0, stream>>>(
            Al, sumdt, Sbuf);
        scan3_g<<<dim3(8, NCHUNK), dim3(256), 0, stream>>>(
            dt_bf, xc_bf, dbl, xz_bf, Al, p.D_skip + layer * DINNER, Sbuf, y_bf);
        gemm_g<2, 2, 2><<<dim3(16, 32), dim3(256), 0, stream>>>(
            y_bf, DINNER, out_w_bf + (size_t)layer * DMODEL * DINNER, DINNER,
            buf_x, nullptr, DMODEL, DMODEL, DINNER, resid_src);
    }
    ln_g<<<dim3(NBLK), dim3(256), 0, stream>>>(buf_x, p.nf_w, p.nf_b,
                                               (float*)d_out, nullptr);
}

// Round 5
// 476.076 us; speedup vs baseline: 2.4819x; 2.4819x over previous
//
#include <hip/hip_runtime.h>
#include <hip/hip_bf16.h>
#include <math.h>

// Problem constants
#define LSEQ 2048
#define DMODEL 1024
#define DINNER 2048
#define DSTATE 16
#define DCONV 4
#define DTRANK 64
#define RPROJ 96   // DTRANK + 2*DSTATE

// Chunked-scan decomposition
#define CHUNK 32
#define NCHUNK (LSEQ / CHUNK)   // 64

#define XSPLIT 4                // split-K factor for x_proj

typedef __attribute__((ext_vector_type(8))) short bf16x8;
typedef __attribute__((ext_vector_type(4))) float f32x4;

__device__ __forceinline__ float softplusf(float x) {
    return (x > 20.f) ? x : log1pf(__expf(x));
}
__device__ __forceinline__ float siluf(float x) {
    return x / (1.f + __expf(-x));
}
// f32 -> bf16 RTNE
__device__ __forceinline__ short f2bf(float f) {
    union { float f; unsigned u; } v; v.f = f;
    unsigned r = v.u + 0x7FFFu + ((v.u >> 16) & 1u);
    return (short)(r >> 16);
}
// bf16 -> f32
__device__ __forceinline__ float bf2f(short h) {
    union { unsigned u; float f; } v;
    v.u = ((unsigned)(unsigned short)h) << 16;
    return v.f;
}

__device__ __forceinline__ void cvt8(const float* __restrict__ s,
                                     short* __restrict__ d, int i) {
    const float4 a = *(const float4*)(s + i);
    const float4 b = *(const float4*)(s + i + 4);
    alignas(16) short h[8];
    h[0] = f2bf(a.x); h[1] = f2bf(a.y); h[2] = f2bf(a.z); h[3] = f2bf(a.w);
    h[4] = f2bf(b.x); h[5] = f2bf(b.y); h[6] = f2bf(b.z); h[7] = f2bf(b.w);
    *(uint4*)(d + i) = *(const uint4*)h;
}

// ---------------- LayerNorm phase: one wave per row ----------------------
__device__ __forceinline__ void ln_phase(
    const float* __restrict__ x, const float* __restrict__ w,
    const float* __restrict__ b, float* __restrict__ outf,
    short* __restrict__ outb, int bid, int tid)
{
    const int wv = tid >> 6, lane = tid & 63;
    const int row = bid * 4 + wv;
    const float* xr = x + (size_t)row * DMODEL;
    float v[16];
    float s = 0.f, sq = 0.f;
#pragma unroll
    for (int k = 0; k < 16; k++) {
        v[k] = xr[k * 64 + lane];
        s += v[k];
        sq += v[k] * v[k];
    }
#pragma unroll
    for (int off = 32; off > 0; off >>= 1) {
        s += __shfl_xor(s, off, 64);
        sq += __shfl_xor(sq, off, 64);
    }
    const float mu = s * (1.f / DMODEL);
    const float var = sq * (1.f / DMODEL) - mu * mu;
    const float rstd = rsqrtf(var + 1e-5f);
#pragma unroll
    for (int k = 0; k < 16; k++) {
        const int i = k * 64 + lane;
        const float o = (v[k] - mu) * rstd * w[i] + b[i];
        if (outf) outf[(size_t)row * DMODEL + i] = o;
        else      outb[(size_t)row * DMODEL + i] = f2bf(o);
    }
}

// ---- fused f32->bf16 weight convert (all tensors) + layer-0 LayerNorm ---
__global__ __launch_bounds__(256) void cvt_ln_kernel(
    const float* __restrict__ in_w, short* __restrict__ in_w_bf,
    const float* __restrict__ xp_w, short* __restrict__ xp_w_bf,
    const float* __restrict__ out_w, short* __restrict__ out_w_bf,
    const float* __restrict__ dtp_w, short* __restrict__ dtp_w_bf,
    const float* __restrict__ x_in, const float* __restrict__ ln_w,
    const float* __restrict__ ln_b, short* __restrict__ h_bf)
{
    const int n1 = 2 * (2 * DINNER) * DMODEL;
    const int n2 = 2 * RPROJ * DINNER;
    const int n3 = 2 * DMODEL * DINNER;
    const int bid = blockIdx.x;
    const int tid = threadIdx.x;
    {
        int i = (bid * 256 + tid) * 8;
        if (i < n1) { cvt8(in_w, in_w_bf, i); goto done_cvt; }
        i -= n1;
        if (i < n2) { cvt8(xp_w, xp_w_bf, i); goto done_cvt; }
        i -= n2;
        if (i < n3) { cvt8(out_w, out_w_bf, i); goto done_cvt; }
        i -= n3;
        cvt8(dtp_w, dtp_w_bf, i);
    }
done_cvt:
    if (bid < LSEQ / 4)   // layer-0 LayerNorm (independent inputs)
        ln_phase(x_in, ln_w, ln_b, nullptr, h_bf, bid, tid);
}

// ---------------- LayerNorm standalone -----------------------------------
__global__ __launch_bounds__(256) void ln_g(
    const float* __restrict__ x, const float* __restrict__ w,
    const float* __restrict__ b, float* __restrict__ outf,
    short* __restrict__ outb)
{
    ln_phase(x, w, b, outf, outb, blockIdx.x, threadIdx.x);
}

// ------ bf16 MFMA NT GEMM, (32*MI)x(32*NJ) tile, BK=64, XOR-swizzle ------
// MODE 2: f32 (. + resid)   MODE 3: bf16 store   MODE 6: atomicAdd f32
template<int MI, int NJ, int MODE>
__global__ __launch_bounds__(256) void gemm_g(
    const short* __restrict__ A, int lda,
    const short* __restrict__ W, int ldw,
    float* __restrict__ Cf, short* __restrict__ Cb, int ldc,
    int N, int K, const float* __restrict__ resid)
{
    constexpr int BM = 32 * MI;
    constexpr int BN = 32 * NJ;
    constexpr int AISS = BM / 32;
    constexpr int WISS = BN / 32;
    __shared__ alignas(16) short As[BM * 64];
    __shared__ alignas(16) short Ws[BN * 64];

    const int tid = threadIdx.x;
    const int lane = tid & 63;
    const int w = tid >> 6;
    const int wr = w >> 1, wc = w & 1;
    const int row0 = blockIdx.y * BM;
    const int col0 = blockIdx.x * BN;
    const int kbeg = blockIdx.z * K;

    const int srow = tid >> 3;                       // 0..31
    const int dch  = tid & 7;                        // dest chunk 0..7
    const int skch = (dch ^ (srow & 7)) * 8;         // swizzled source col

    f32x4 acc[MI][NJ];
#pragma unroll
    for (int i = 0; i < MI; i++)
#pragma unroll
        for (int j = 0; j < NJ; j++) acc[i][j] = (f32x4)0.f;

    const int lrow = lane & 15;
    const int q = lane >> 4;

    for (int kt = kbeg; kt < kbeg + K; kt += 64) {
        __syncthreads();
#pragma unroll
        for (int j = 0; j < AISS; j++) {
            const short* gp = A + (size_t)(row0 + j * 32 + srow) * lda + kt + skch;
            __builtin_amdgcn_global_load_lds(
                (const __attribute__((address_space(1))) void*)gp,
                (__attribute__((address_space(3))) void*)(&As[j * 2048 + tid * 8]),
                16, 0, 0);
        }
#pragma unroll
        for (int j = 0; j < WISS; j++) {
            const int wrow = col0 + j * 32 + srow;
            if (wrow < N) {
                const short* gp = W + (size_t)wrow * ldw + kt + skch;
                __builtin_amdgcn_global_load_lds(
                    (const __attribute__((address_space(1))) void*)gp,
                    (__attribute__((address_space(3))) void*)(&Ws[j * 2048 + tid * 8]),
                    16, 0, 0);
            }
        }
        __syncthreads();

#pragma unroll
        for (int ks = 0; ks < 2; ks++) {
            bf16x8 af[MI], bfr[NJ];
#pragma unroll
            for (int i = 0; i < MI; i++) {
                const int R = wr * (16 * MI) + i * 16 + lrow;
                const int pc = (ks * 4 + q) ^ (R & 7);
                af[i] = *(const bf16x8*)&As[R * 64 + pc * 8];
            }
#pragma unroll
            for (int j = 0; j < NJ; j++) {
                const int R = wc * (16 * NJ) + j * 16 + lrow;
                const int pc = (ks * 4 + q) ^ (R & 7);
                bfr[j] = *(const bf16x8*)&Ws[R * 64 + pc * 8];
            }
#pragma unroll
            for (int i = 0; i < MI; i++)
#pragma unroll
                for (int j = 0; j < NJ; j++)
                    acc[i][j] = __builtin_amdgcn_mfma_f32_16x16x32_bf16(
                        af[i], bfr[j], acc[i][j], 0, 0, 0);
        }
    }

    // epilogue: C/D layout col=lane&15, row=(lane>>4)*4+reg
    const int rbase = row0 + wr * (16 * MI);
    const int cbase = col0 + wc * (16 * NJ);
#pragma unroll
    for (int i = 0; i < MI; i++) {
#pragma unroll
        for (int j = 0; j < NJ; j++) {
            const int gcol = cbase + j * 16 + lrow;
            if (gcol < N) {
#pragma unroll
                for (int r = 0; r < 4; r++) {
                    const int grow = rbase + i * 16 + (lane >> 4) * 4 + r;
                    float v = acc[i][j][r];
                    if (MODE == 2) {
                        Cf[(size_t)grow * ldc + gcol] =
                            v + resid[(size_t)grow * ldc + gcol];
                    } else if (MODE == 3) {
                        Cb[(size_t)grow * ldc + gcol] = f2bf(v);
                    } else {  // MODE 6: split-K accumulate
                        atomicAdd(&Cf[(size_t)grow * ldc + gcol], v);
                    }
                }
            }
        }
    }
}

// ---------- dt_proj: 64x128 tile, K=64; A staged from f32 dbl ------------
__global__ __launch_bounds__(256) void dtproj_g(
    const float* __restrict__ dbl,      // [L,RPROJ] f32 (cols 0..63 used)
    const short* __restrict__ dtp_w,    // [DINNER,64] bf16
    const float* __restrict__ dtp_b,    // [DINNER]
    short* __restrict__ dt_bf)          // [L,DINNER]
{
    __shared__ alignas(16) short As[64 * 32];
    __shared__ alignas(16) short Ws[128 * 32];
    const int tid = threadIdx.x;
    const int lane = tid & 63;
    const int w = tid >> 6;
    const int wr = w >> 1, wc = w & 1;
    const int row0 = blockIdx.y * 64;
    const int col0 = blockIdx.x * 128;
    const int srow = tid >> 2;
    const int skch = ((tid & 3) ^ ((srow >> 1) & 3)) * 8;
    const int lrow = lane & 15;
    const int q = lane >> 4;

    f32x4 acc[2][4];
#pragma unroll
    for (int i = 0; i < 2; i++)
#pragma unroll
        for (int j = 0; j < 4; j++) acc[i][j] = (f32x4)0.f;

#pragma unroll
    for (int kt = 0; kt < 64; kt += 32) {
        __syncthreads();
        {
            const float* gp = dbl + (size_t)(row0 + srow) * RPROJ + kt + skch;
            const float4 a = *(const float4*)gp;
            const float4 b = *(const float4*)(gp + 4);
            alignas(16) short h[8];
            h[0] = f2bf(a.x); h[1] = f2bf(a.y); h[2] = f2bf(a.z); h[3] = f2bf(a.w);
            h[4] = f2bf(b.x); h[5] = f2bf(b.y); h[6] = f2bf(b.z); h[7] = f2bf(b.w);
            *(uint4*)(As + tid * 8) = *(const uint4*)h;
        }
#pragma unroll
        for (int j = 0; j < 2; j++) {
            const short* gp = dtp_w + (size_t)(col0 + j * 64 + srow) * DTRANK + kt + skch;
            __builtin_amdgcn_global_load_lds(
                (const __attribute__((address_space(1))) void*)gp,
                (__attribute__((address_space(3))) void*)(&Ws[j * 2048 + tid * 8]),
                16, 0, 0);
        }
        __syncthreads();

        bf16x8 af[2], bfr[4];
#pragma unroll
        for (int i = 0; i < 2; i++) {
            const int R = wr * 32 + i * 16 + lrow;
            af[i] = *(const bf16x8*)&As[R * 32 + ((q ^ ((R >> 1) & 3)) * 8)];
        }
#pragma unroll
        for (int j = 0; j < 4; j++) {
            const int R = wc * 64 + j * 16 + lrow;
            bfr[j] = *(const bf16x8*)&Ws[R * 32 + ((q ^ ((R >> 1) & 3)) * 8)];
        }
#pragma unroll
        for (int i = 0; i < 2; i++)
#pragma unroll
            for (int j = 0; j < 4; j++)
                acc[i][j] = __builtin_amdgcn_mfma_f32_16x16x32_bf16(
                    af[i], bfr[j], acc[i][j], 0, 0, 0);
    }

    const int rbase = row0 + wr * 32;
    const int cbase = col0 + wc * 64;
#pragma unroll
    for (int i = 0; i < 2; i++)
#pragma unroll
        for (int j = 0; j < 4; j++) {
            const int gcol = cbase + j * 16 + lrow;
#pragma unroll
            for (int r = 0; r < 4; r++) {
                const int grow = rbase + i * 16 + (lane >> 4) * 4 + r;
                dt_bf[(size_t)grow * DINNER + gcol] =
                    f2bf(softplusf(acc[i][j][r] + dtp_b[gcol]));
            }
        }
}

// ---------------- Causal depthwise conv (k=4) + bias + silu --------------
// Also zero-fills dbl (d_ws is poisoned) so x_proj can atomicAdd into it.
__global__ __launch_bounds__(256) void conv_g(
    const short* __restrict__ xzb, const float* __restrict__ cw,
    const float* __restrict__ cb, short* __restrict__ xcb,
    float* __restrict__ dbl_zero)
{
    const int g = blockIdx.x * 256 + threadIdx.x;   // over L * DINNER/8
    if (g < (LSEQ * RPROJ) / 4)
        *(float4*)(dbl_zero + g * 4) = make_float4(0.f, 0.f, 0.f, 0.f);
    const int t = g >> 8;
    const int c0 = (g & 255) * 8;
    float acc[8];
#pragma unroll
    for (int j = 0; j < 8; j++) acc[j] = cb[c0 + j];
#pragma unroll
    for (int k = 0; k < DCONV; k++) {
        const int tt = t - (DCONV - 1) + k;
        if (tt >= 0) {
            const bf16x8 v = *(const bf16x8*)(xzb + (size_t)tt * (2 * DINNER) + c0);
#pragma unroll
            for (int j = 0; j < 8; j++)
                acc[j] += bf2f(v[j]) * cw[(c0 + j) * DCONV + k];
        }
    }
    alignas(16) short h[8];
#pragma unroll
    for (int j = 0; j < 8; j++) h[j] = f2bf(siluf(acc[j]));
    *(uint4*)(xcb + (size_t)t * DINNER + c0) = *(const uint4*)h;
}

// ============ Chunked selective scan (CHUNK=32) ============
__global__ __launch_bounds__(256) void scan1_g(
    const short* __restrict__ dtb,   // [L, DINNER] bf16
    const short* __restrict__ xcb,   // [L, DINNER] bf16
    const float* __restrict__ dbl,   // [L, RPROJ] f32
    const float* __restrict__ A_log,
    float* __restrict__ S,           // [NCHUNK][DSTATE][DINNER]
    float* __restrict__ sumdt)       // [NCHUNK][DINNER]
{
    const int e = blockIdx.x * 256 + threadIdx.x;
    const int c = blockIdx.y;
    float a[DSTATE];
#pragma unroll
    for (int n = 0; n < DSTATE; n++) a[n] = -__expf(A_log[(size_t)e * DSTATE + n]);
    float h[DSTATE];
#pragma unroll
    for (int n = 0; n < DSTATE; n++) h[n] = 0.f;
    float sd = 0.f;

    __shared__ float sBC[CHUNK][32];
    for (int i = threadIdx.x; i < CHUNK * 32; i += 256) {
        const int tl = i >> 5, j = i & 31;
        sBC[tl][j] = dbl[(size_t)(c * CHUNK + tl) * RPROJ + DTRANK + j];
    }
    __syncthreads();

    const size_t rb = (size_t)c * CHUNK * DINNER + e;
    short dt_c = dtb[rb], xc_c = xcb[rb];
#pragma unroll 4
    for (int tl = 0; tl < CHUNK; tl++) {
        short dt_n = 0, xc_n = 0;
        if (tl + 1 < CHUNK) {
            dt_n = dtb[rb + (size_t)(tl + 1) * DINNER];
            xc_n = xcb[rb + (size_t)(tl + 1) * DINNER];
        }
        const float dtv = bf2f(dt_c);
        const float du = dtv * bf2f(xc_c);
        sd += dtv;
#pragma unroll
        for (int n = 0; n < DSTATE; n++) {
            const float dA = __expf(dtv * a[n]);
            h[n] = dA * h[n] + du * sBC[tl][n];
        }
        dt_c = dt_n; xc_c = xc_n;
    }
    sumdt[(size_t)c * DINNER + e] = sd;
#pragma unroll
    for (int n = 0; n < DSTATE; n++)
        S[((size_t)c * DSTATE + n) * DINNER + e] = h[n];
}

// pass2: 4-deep software pipeline over the 64-chunk serial dimension
__global__ __launch_bounds__(256) void scan2_g(
    const float* __restrict__ A_log,
    const float* __restrict__ sumdt,
    float* __restrict__ S)
{
    const int idx = blockIdx.x * 256 + threadIdx.x;
    const int e = idx & (DINNER - 1);
    const int n = idx >> 11;
    const float a = -__expf(A_log[(size_t)e * DSTATE + n]);
    const size_t base = (size_t)n * DINNER + e;
    const size_t cstr = (size_t)DSTATE * DINNER;
    float H = 0.f;
    for (int c = 0; c < NCHUNK; c += 4) {
        const float sc0 = S[base + (size_t)(c + 0) * cstr];
        const float sc1 = S[base + (size_t)(c + 1) * cstr];
        const float sc2 = S[base + (size_t)(c + 2) * cstr];
        const float sc3 = S[base + (size_t)(c + 3) * cstr];
        const float sd0 = sumdt[(size_t)(c + 0) * DINNER + e];
        const float sd1 = sumdt[(size_t)(c + 1) * DINNER + e];
        const float sd2 = sumdt[(size_t)(c + 2) * DINNER + e];
        const float sd3 = sumdt[(size_t)(c + 3) * DINNER + e];
        S[base + (size_t)(c + 0) * cstr] = H;
        H = __expf(a * sd0) * H + sc0;
        S[base + (size_t)(c + 1) * cstr] = H;
        H = __expf(a * sd1) * H + sc1;
        S[base + (size_t)(c + 2) * cstr] = H;
        H = __expf(a * sd2) * H + sc2;
        S[base + (size_t)(c + 3) * cstr] = H;
        H = __expf(a * sd3) * H + sc3;
    }
}

__global__ __launch_bounds__(256) void scan3_g(
    const short* __restrict__ dtb,
    const short* __restrict__ xcb,
    const float* __restrict__ dbl,
    const short* __restrict__ xzb,   // z at cols DINNER.. (bf16)
    const float* __restrict__ A_log,
    const float* __restrict__ Dp,
    const float* __restrict__ S,
    short* __restrict__ yb)
{
    const int e = blockIdx.x * 256 + threadIdx.x;
    const int c = blockIdx.y;
    float a[DSTATE];
#pragma unroll
    for (int n = 0; n < DSTATE; n++) a[n] = -__expf(A_log[(size_t)e * DSTATE + n]);
    float h[DSTATE];
#pragma unroll
    for (int n = 0; n < DSTATE; n++)
        h[n] = S[((size_t)c * DSTATE + n) * DINNER + e];
    const float dskip = Dp[e];

    __shared__ float sBC[CHUNK][32];
    for (int i = threadIdx.x; i < CHUNK * 32; i += 256) {
        const int tl = i >> 5, j = i & 31;
        sBC[tl][j] = dbl[(size_t)(c * CHUNK + tl) * RPROJ + DTRANK + j];
    }
    __syncthreads();

    const size_t rb = (size_t)c * CHUNK * DINNER + e;
    const size_t zb = (size_t)c * CHUNK * (2 * DINNER) + DINNER + e;
    short dt_c = dtb[rb], xc_c = xcb[rb], z_c = xzb[zb];
#pragma unroll 4
    for (int tl = 0; tl < CHUNK; tl++) {
        short dt_n = 0, xc_n = 0, z_n = 0;
        if (tl + 1 < CHUNK) {
            dt_n = dtb[rb + (size_t)(tl + 1) * DINNER];
            xc_n = xcb[rb + (size_t)(tl + 1) * DINNER];
            z_n = xzb[zb + (size_t)(tl + 1) * (2 * DINNER)];
        }
        const float dtv = bf2f(dt_c);
        const float xcv = bf2f(xc_c);
        const float du = dtv * xcv;
        float yv = 0.f;
#pragma unroll
        for (int n = 0; n < DSTATE; n++) {
            const float dA = __expf(dtv * a[n]);
            h[n] = dA * h[n] + du * sBC[tl][n];
            yv += h[n] * sBC[tl][16 + n];
        }
        yv = (yv + xcv * dskip) * siluf(bf2f(z_c));
        yb[rb + (size_t)tl * DINNER] = f2bf(yv);
        dt_c = dt_n; xc_c = xc_n; z_c = z_n;
    }
}

extern "C" void kernel_launch(void* const* d_in, const int* in_sizes, int n_in,
                              void* d_out, int out_size, void* d_ws, size_t ws_size,
                              hipStream_t stream) {
    const float* x_in   = (const float*)d_in[0];
    const float* ln_w   = (const float*)d_in[1];
    const float* ln_b   = (const float*)d_in[2];
    const float* in_w   = (const float*)d_in[3];
    const float* conv_w = (const float*)d_in[4];
    const float* conv_b = (const float*)d_in[5];
    const float* xp_w   = (const float*)d_in[6];
    const float* dtp_w  = (const float*)d_in[7];
    const float* dtp_b  = (const float*)d_in[8];
    const float* A_log  = (const float*)d_in[9];
    const float* D_skip = (const float*)d_in[10];
    const float* out_w  = (const float*)d_in[11];
    const float* nf_w   = (const float*)d_in[12];
    const float* nf_b   = (const float*)d_in[13];
    float* out = (float*)d_out;

    float* w = (float*)d_ws;
    float* buf_x = w; w += (size_t)LSEQ * DMODEL;              // residual stream (f32)
    float* dbl   = w; w += (size_t)LSEQ * RPROJ;               // x_proj out (f32)
    float* Sbuf  = w; w += (size_t)NCHUNK * DSTATE * DINNER;   // chunk summaries
    float* sumdt = w; w += (size_t)NCHUNK * DINNER;
    // bf16 buffers (sized in float units, 2 shorts per float)
    short* h_bf    = (short*)w; w += (size_t)LSEQ * DMODEL / 2;
    short* xz_bf   = (short*)w; w += (size_t)LSEQ * 2 * DINNER / 2;
    short* xc_bf   = (short*)w; w += (size_t)LSEQ * DINNER / 2;
    short* dt_bf   = (short*)w; w += (size_t)LSEQ * DINNER / 2;
    short* y_bf    = (short*)w; w += (size_t)LSEQ * DINNER / 2;
    short* in_w_bf  = (short*)w; w += (size_t)2 * (2 * DINNER) * DMODEL / 2;
    short* xp_w_bf  = (short*)w; w += (size_t)2 * RPROJ * DINNER / 2;
    short* dtp_w_bf = (short*)w; w += (size_t)2 * DINNER * DTRANK / 2;
    short* out_w_bf = (short*)w; w += (size_t)2 * DMODEL * DINNER / 2;

    // fused: weight conversion (all layers, 4 tensors) + layer-0 LayerNorm
    {
        const int total = 2 * (2 * DINNER) * DMODEL + 2 * RPROJ * DINNER
                        + 2 * DMODEL * DINNER + 2 * DINNER * DTRANK;  // 13238272
        cvt_ln_kernel<<<dim3(total / (256 * 8)), dim3(256), 0, stream>>>(
            in_w, in_w_bf, xp_w, xp_w_bf, out_w, out_w_bf, dtp_w, dtp_w_bf,
            x_in, ln_w, ln_b, h_bf);
    }

    for (int layer = 0; layer < 2; layer++) {
        const float* resid_src = (layer == 0) ? x_in : buf_x;
        // 1. LayerNorm -> bf16 (layer 0 already done in cvt_ln_kernel)
        if (layer > 0)
            ln_g<<<dim3(LSEQ / 4), dim3(256), 0, stream>>>(
                resid_src, ln_w + layer * DMODEL, ln_b + layer * DMODEL,
                nullptr, h_bf);
        // 2. in_proj (MFMA 128x128 BK=64, bf16 out)
        gemm_g<4, 4, 3><<<dim3((2 * DINNER) / 128, LSEQ / 128), dim3(256), 0, stream>>>(
            h_bf, DMODEL, in_w_bf + (size_t)layer * 2 * DINNER * DMODEL, DMODEL,
            nullptr, xz_bf, 2 * DINNER, 2 * DINNER, DMODEL, nullptr);
        // 3. conv + silu -> bf16 (also zero-fills dbl for the atomic split-K)
        conv_g<<<dim3((LSEQ * DINNER / 8) / 256), dim3(256), 0, stream>>>(
            xz_bf, conv_w + (size_t)layer * DINNER * DCONV, conv_b + layer * DINNER,
            xc_bf, dbl);
        // 4. x_proj (MFMA 64x64 BK=64, split-K=4, atomicAdd into dbl)
        gemm_g<2, 2, 6><<<dim3(2, LSEQ / 64, XSPLIT), dim3(256), 0, stream>>>(
            xc_bf, DINNER, xp_w_bf + (size_t)layer * RPROJ * DINNER, DINNER,
            dbl, nullptr, RPROJ, RPROJ, DINNER / XSPLIT, nullptr);
        // 5. dt_proj (64x128, K=64, A from f32 dbl, softplus+bias -> bf16)
        dtproj_g<<<dim3(DINNER / 128, LSEQ / 64), dim3(256), 0, stream>>>(
            dbl, dtp_w_bf + (size_t)layer * DINNER * DTRANK,
            dtp_b + layer * DINNER, dt_bf);
        // 6. chunked selective scan (+ skip + z-gate) -> y_bf
        const float* Al = A_log + (size_t)layer * DINNER * DSTATE;
        scan1_g<<<dim3(DINNER / 256, NCHUNK), dim3(256), 0, stream>>>(
            dt_bf, xc_bf, dbl, Al, Sbuf, sumdt);
        scan2_g<<<dim3((DINNER * DSTATE) / 256), dim3(256), 0, stream>>>(
            Al, sumdt, Sbuf);
        scan3_g<<<dim3(DINNER / 256, NCHUNK), dim3(256), 0, stream>>>(
            dt_bf, xc_bf, dbl, xz_bf, Al, D_skip + layer * DINNER, Sbuf, y_bf);
        // 7. out_proj (MFMA 128x64 BK=64) + residual -> buf_x f32
        gemm_g<4, 2, 2><<<dim3(DMODEL / 64, LSEQ / 128), dim3(256), 0, stream>>>(
            y_bf, DINNER, out_w_bf + (size_t)layer * DMODEL * DINNER, DINNER,
            buf_x, nullptr, DMODEL, DMODEL, DINNER, resid_src);
    }
    // final LayerNorm -> d_out (f32)
    ln_g<<<dim3(LSEQ / 4), dim3(256), 0, stream>>>(buf_x, nf_w, nf_b, out, nullptr);
}

// Round 6
// 457.803 us; speedup vs baseline: 2.5809x; 1.0399x over previous
//
#include <hip/hip_runtime.h>
#include <hip/hip_bf16.h>
#include <math.h>

// Problem constants
#define LSEQ 2048
#define DMODEL 1024
#define DINNER 2048
#define DSTATE 16
#define DCONV 4
#define DTRANK 64
#define RPROJ 96   // DTRANK + 2*DSTATE

// Chunked-scan decomposition
#define CHUNK 16
#define NCHUNK (LSEQ / CHUNK)   // 128

#define XSPLIT 4                // split-K factor for x_proj
#define XKS (DINNER / XSPLIT)   // 512 channels per split

typedef __attribute__((ext_vector_type(8))) short bf16x8;
typedef __attribute__((ext_vector_type(4))) float f32x4;

__device__ __forceinline__ float softplusf(float x) {
    return (x > 20.f) ? x : log1pf(__expf(x));
}
__device__ __forceinline__ float siluf(float x) {
    return x / (1.f + __expf(-x));
}
// f32 -> bf16 RTNE
__device__ __forceinline__ short f2bf(float f) {
    union { float f; unsigned u; } v; v.f = f;
    unsigned r = v.u + 0x7FFFu + ((v.u >> 16) & 1u);
    return (short)(r >> 16);
}
// bf16 -> f32
__device__ __forceinline__ float bf2f(short h) {
    union { unsigned u; float f; } v;
    v.u = ((unsigned)(unsigned short)h) << 16;
    return v.f;
}

__device__ __forceinline__ void cvt8(const float* __restrict__ s,
                                     short* __restrict__ d, int i) {
    const float4 a = *(const float4*)(s + i);
    const float4 b = *(const float4*)(s + i + 4);
    alignas(16) short h[8];
    h[0] = f2bf(a.x); h[1] = f2bf(a.y); h[2] = f2bf(a.z); h[3] = f2bf(a.w);
    h[4] = f2bf(b.x); h[5] = f2bf(b.y); h[6] = f2bf(b.z); h[7] = f2bf(b.w);
    *(uint4*)(d + i) = *(const uint4*)h;
}

// ---------------- LayerNorm phase: one wave per row ----------------------
__device__ __forceinline__ void ln_phase(
    const float* __restrict__ x, const float* __restrict__ w,
    const float* __restrict__ b, float* __restrict__ outf,
    short* __restrict__ outb, int bid, int tid)
{
    const int wv = tid >> 6, lane = tid & 63;
    const int row = bid * 4 + wv;
    const float* xr = x + (size_t)row * DMODEL;
    float v[16];
    float s = 0.f, sq = 0.f;
#pragma unroll
    for (int k = 0; k < 16; k++) {
        v[k] = xr[k * 64 + lane];
        s += v[k];
        sq += v[k] * v[k];
    }
#pragma unroll
    for (int off = 32; off > 0; off >>= 1) {
        s += __shfl_xor(s, off, 64);
        sq += __shfl_xor(sq, off, 64);
    }
    const float mu = s * (1.f / DMODEL);
    const float var = sq * (1.f / DMODEL) - mu * mu;
    const float rstd = rsqrtf(var + 1e-5f);
#pragma unroll
    for (int k = 0; k < 16; k++) {
        const int i = k * 64 + lane;
        const float o = (v[k] - mu) * rstd * w[i] + b[i];
        if (outf) outf[(size_t)row * DMODEL + i] = o;
        else      outb[(size_t)row * DMODEL + i] = f2bf(o);
    }
}

// ---- fused f32->bf16 weight convert (all tensors) + layer-0 LayerNorm ---
__global__ __launch_bounds__(256) void cvt_ln_kernel(
    const float* __restrict__ in_w, short* __restrict__ in_w_bf,
    const float* __restrict__ xp_w, short* __restrict__ xp_w_bf,
    const float* __restrict__ out_w, short* __restrict__ out_w_bf,
    const float* __restrict__ dtp_w, short* __restrict__ dtp_w_bf,
    const float* __restrict__ x_in, const float* __restrict__ ln_w,
    const float* __restrict__ ln_b, short* __restrict__ h_bf)
{
    const int n1 = 2 * (2 * DINNER) * DMODEL;
    const int n2 = 2 * RPROJ * DINNER;
    const int n3 = 2 * DMODEL * DINNER;
    const int bid = blockIdx.x;
    const int tid = threadIdx.x;
    {
        int i = (bid * 256 + tid) * 8;
        if (i < n1) { cvt8(in_w, in_w_bf, i); goto done_cvt; }
        i -= n1;
        if (i < n2) { cvt8(xp_w, xp_w_bf, i); goto done_cvt; }
        i -= n2;
        if (i < n3) { cvt8(out_w, out_w_bf, i); goto done_cvt; }
        i -= n3;
        cvt8(dtp_w, dtp_w_bf, i);
    }
done_cvt:
    if (bid < LSEQ / 4)   // layer-0 LayerNorm (independent inputs)
        ln_phase(x_in, ln_w, ln_b, nullptr, h_bf, bid, tid);
}

// ---------------- LayerNorm standalone -----------------------------------
__global__ __launch_bounds__(256) void ln_g(
    const float* __restrict__ x, const float* __restrict__ w,
    const float* __restrict__ b, float* __restrict__ outf,
    short* __restrict__ outb)
{
    ln_phase(x, w, b, outf, outb, blockIdx.x, threadIdx.x);
}

// ------ bf16 MFMA NT GEMM, (32*MI)x(32*NJ) tile, BK=64, XOR-swizzle ------
// MODE 2: f32 (. + resid)   MODE 3: bf16 store
// zbuf/zcount4: optional float4 zero-fill fused into the epilogue.
template<int MI, int NJ, int MODE>
__global__ __launch_bounds__(256) void gemm_g(
    const short* __restrict__ A, int lda,
    const short* __restrict__ W, int ldw,
    float* __restrict__ Cf, short* __restrict__ Cb, int ldc,
    int N, int K, const float* __restrict__ resid,
    float* __restrict__ zbuf, int zcount4)
{
    constexpr int BM = 32 * MI;
    constexpr int BN = 32 * NJ;
    constexpr int AISS = BM / 32;
    constexpr int WISS = BN / 32;
    __shared__ alignas(16) short As[BM * 64];
    __shared__ alignas(16) short Ws[BN * 64];

    const int tid = threadIdx.x;
    const int lane = tid & 63;
    const int w = tid >> 6;
    const int wr = w >> 1, wc = w & 1;
    const int row0 = blockIdx.y * BM;
    const int col0 = blockIdx.x * BN;

    const int srow = tid >> 3;                       // 0..31
    const int dch  = tid & 7;                        // dest chunk 0..7
    const int skch = (dch ^ (srow & 7)) * 8;         // swizzled source col

    f32x4 acc[MI][NJ];
#pragma unroll
    for (int i = 0; i < MI; i++)
#pragma unroll
        for (int j = 0; j < NJ; j++) acc[i][j] = (f32x4)0.f;

    const int lrow = lane & 15;
    const int q = lane >> 4;

    for (int kt = 0; kt < K; kt += 64) {
        __syncthreads();
#pragma unroll
        for (int j = 0; j < AISS; j++) {
            const short* gp = A + (size_t)(row0 + j * 32 + srow) * lda + kt + skch;
            __builtin_amdgcn_global_load_lds(
                (const __attribute__((address_space(1))) void*)gp,
                (__attribute__((address_space(3))) void*)(&As[j * 2048 + tid * 8]),
                16, 0, 0);
        }
#pragma unroll
        for (int j = 0; j < WISS; j++) {
            const int wrow = col0 + j * 32 + srow;
            if (wrow < N) {
                const short* gp = W + (size_t)wrow * ldw + kt + skch;
                __builtin_amdgcn_global_load_lds(
                    (const __attribute__((address_space(1))) void*)gp,
                    (__attribute__((address_space(3))) void*)(&Ws[j * 2048 + tid * 8]),
                    16, 0, 0);
            }
        }
        __syncthreads();

#pragma unroll
        for (int ks = 0; ks < 2; ks++) {
            bf16x8 af[MI], bfr[NJ];
#pragma unroll
            for (int i = 0; i < MI; i++) {
                const int R = wr * (16 * MI) + i * 16 + lrow;
                const int pc = (ks * 4 + q) ^ (R & 7);
                af[i] = *(const bf16x8*)&As[R * 64 + pc * 8];
            }
#pragma unroll
            for (int j = 0; j < NJ; j++) {
                const int R = wc * (16 * NJ) + j * 16 + lrow;
                const int pc = (ks * 4 + q) ^ (R & 7);
                bfr[j] = *(const bf16x8*)&Ws[R * 64 + pc * 8];
            }
#pragma unroll
            for (int i = 0; i < MI; i++)
#pragma unroll
                for (int j = 0; j < NJ; j++)
                    acc[i][j] = __builtin_amdgcn_mfma_f32_16x16x32_bf16(
                        af[i], bfr[j], acc[i][j], 0, 0, 0);
        }
    }

    // epilogue: C/D layout col=lane&15, row=(lane>>4)*4+reg
    const int rbase = row0 + wr * (16 * MI);
    const int cbase = col0 + wc * (16 * NJ);
#pragma unroll
    for (int i = 0; i < MI; i++) {
#pragma unroll
        for (int j = 0; j < NJ; j++) {
            const int gcol = cbase + j * 16 + lrow;
            if (gcol < N) {
#pragma unroll
                for (int r = 0; r < 4; r++) {
                    const int grow = rbase + i * 16 + (lane >> 4) * 4 + r;
                    float v = acc[i][j][r];
                    if (MODE == 2) {
                        Cf[(size_t)grow * ldc + gcol] =
                            v + resid[(size_t)grow * ldc + gcol];
                    } else {  // MODE 3
                        Cb[(size_t)grow * ldc + gcol] = f2bf(v);
                    }
                }
            }
        }
    }
    // fused zero-fill (e.g. dbl before x_proj's atomic split-K)
    if (zbuf) {
        const int g = (blockIdx.y * gridDim.x + blockIdx.x) * 256 + tid;
        if (g < zcount4)
            *(float4*)(zbuf + (size_t)g * 4) = make_float4(0.f, 0.f, 0.f, 0.f);
    }
}

// ---- x_proj with FUSED conv+silu A-staging, 64x64 tile, split-K=4 -------
// A[t, ch] = silu(conv(xz)[t, ch]) computed in registers from xz, written
// to the same swizzled LDS slots the async path used. atomicAdd epilogue.
__global__ __launch_bounds__(256) void xproj_conv_g(
    const short* __restrict__ xzb,      // [L, 2*DINNER] bf16 (xc = cols 0..2047)
    const float* __restrict__ cw,       // [DINNER][DCONV] f32
    const float* __restrict__ cb,       // [DINNER]
    const short* __restrict__ W,        // xp_w_bf [RPROJ, DINNER]
    float* __restrict__ dbl)            // [L, RPROJ] f32 (atomicAdd)
{
    __shared__ alignas(16) short As[64 * 64];
    __shared__ alignas(16) short Ws[64 * 64];
    __shared__ float cw4[XKS][4];
    __shared__ float cbl[XKS];

    const int tid = threadIdx.x;
    const int lane = tid & 63;
    const int w = tid >> 6;
    const int wr = w >> 1, wc = w & 1;
    const int row0 = blockIdx.y * 64;
    const int col0 = blockIdx.x * 64;
    const int kbeg = blockIdx.z * XKS;
    const int srow = tid >> 3;
    const int dch  = tid & 7;
    const int skch = (dch ^ (srow & 7)) * 8;
    const int lrow = lane & 15;
    const int q = lane >> 4;

    // stage conv weights/bias for this K-slice (synced by first loop barrier)
    {
        const float4* cwsrc = (const float4*)cw;   // one float4 per channel
        *(float4*)&cw4[tid * 2][0]     = cwsrc[kbeg + tid * 2];
        *(float4*)&cw4[tid * 2 + 1][0] = cwsrc[kbeg + tid * 2 + 1];
        cbl[tid]       = cb[kbeg + tid];
        cbl[tid + 256] = cb[kbeg + tid + 256];
    }

    f32x4 acc[2][2];
#pragma unroll
    for (int i = 0; i < 2; i++)
#pragma unroll
        for (int j = 0; j < 2; j++) acc[i][j] = (f32x4)0.f;

    for (int kt = kbeg; kt < kbeg + XKS; kt += 64) {
        __syncthreads();
        // A: fused conv+silu from xz -> bf16 -> swizzled LDS slot
#pragma unroll
        for (int j = 0; j < 2; j++) {
            const int t = row0 + j * 32 + srow;
            const int ch0 = kt + skch;
            const int lc = ch0 - kbeg;
            float a8[8];
#pragma unroll
            for (int i = 0; i < 8; i++) a8[i] = cbl[lc + i];
#pragma unroll
            for (int k = 0; k < DCONV; k++) {
                const int tt = t - (DCONV - 1) + k;
                if (tt >= 0) {
                    const bf16x8 v = *(const bf16x8*)(xzb + (size_t)tt * (2 * DINNER) + ch0);
#pragma unroll
                    for (int i = 0; i < 8; i++)
                        a8[i] += bf2f(v[i]) * cw4[lc + i][k];
                }
            }
            alignas(16) short h8[8];
#pragma unroll
            for (int i = 0; i < 8; i++) h8[i] = f2bf(siluf(a8[i]));
            *(uint4*)(&As[j * 2048 + tid * 8]) = *(const uint4*)h8;
        }
        // W via async LDS copy (rows >= RPROJ skipped; results discarded)
#pragma unroll
        for (int j = 0; j < 2; j++) {
            const int wrow = col0 + j * 32 + srow;
            if (wrow < RPROJ) {
                const short* gp = W + (size_t)wrow * DINNER + kt + skch;
                __builtin_amdgcn_global_load_lds(
                    (const __attribute__((address_space(1))) void*)gp,
                    (__attribute__((address_space(3))) void*)(&Ws[j * 2048 + tid * 8]),
                    16, 0, 0);
            }
        }
        __syncthreads();

#pragma unroll
        for (int ks = 0; ks < 2; ks++) {
            bf16x8 af[2], bfr[2];
#pragma unroll
            for (int i = 0; i < 2; i++) {
                const int R = wr * 32 + i * 16 + lrow;
                const int pc = (ks * 4 + q) ^ (R & 7);
                af[i] = *(const bf16x8*)&As[R * 64 + pc * 8];
            }
#pragma unroll
            for (int j = 0; j < 2; j++) {
                const int R = wc * 32 + j * 16 + lrow;
                const int pc = (ks * 4 + q) ^ (R & 7);
                bfr[j] = *(const bf16x8*)&Ws[R * 64 + pc * 8];
            }
#pragma unroll
            for (int i = 0; i < 2; i++)
#pragma unroll
                for (int j = 0; j < 2; j++)
                    acc[i][j] = __builtin_amdgcn_mfma_f32_16x16x32_bf16(
                        af[i], bfr[j], acc[i][j], 0, 0, 0);
        }
    }

    const int rbase = row0 + wr * 32;
    const int cbase = col0 + wc * 32;
#pragma unroll
    for (int i = 0; i < 2; i++)
#pragma unroll
        for (int j = 0; j < 2; j++) {
            const int gcol = cbase + j * 16 + lrow;
            if (gcol < RPROJ) {
#pragma unroll
                for (int r = 0; r < 4; r++) {
                    const int grow = rbase + i * 16 + (lane >> 4) * 4 + r;
                    atomicAdd(&dbl[(size_t)grow * RPROJ + gcol], acc[i][j][r]);
                }
            }
        }
}

// ---------- dt_proj: 64x128 tile, K=64; A staged from f32 dbl ------------
__global__ __launch_bounds__(256) void dtproj_g(
    const float* __restrict__ dbl,      // [L,RPROJ] f32 (cols 0..63 used)
    const short* __restrict__ dtp_w,    // [DINNER,64] bf16
    const float* __restrict__ dtp_b,    // [DINNER]
    short* __restrict__ dt_bf)          // [L,DINNER]
{
    __shared__ alignas(16) short As[64 * 32];
    __shared__ alignas(16) short Ws[128 * 32];
    const int tid = threadIdx.x;
    const int lane = tid & 63;
    const int w = tid >> 6;
    const int wr = w >> 1, wc = w & 1;
    const int row0 = blockIdx.y * 64;
    const int col0 = blockIdx.x * 128;
    const int srow = tid >> 2;
    const int skch = ((tid & 3) ^ ((srow >> 1) & 3)) * 8;
    const int lrow = lane & 15;
    const int q = lane >> 4;

    f32x4 acc[2][4];
#pragma unroll
    for (int i = 0; i < 2; i++)
#pragma unroll
        for (int j = 0; j < 4; j++) acc[i][j] = (f32x4)0.f;

#pragma unroll
    for (int kt = 0; kt < 64; kt += 32) {
        __syncthreads();
        {
            const float* gp = dbl + (size_t)(row0 + srow) * RPROJ + kt + skch;
            const float4 a = *(const float4*)gp;
            const float4 b = *(const float4*)(gp + 4);
            alignas(16) short h[8];
            h[0] = f2bf(a.x); h[1] = f2bf(a.y); h[2] = f2bf(a.z); h[3] = f2bf(a.w);
            h[4] = f2bf(b.x); h[5] = f2bf(b.y); h[6] = f2bf(b.z); h[7] = f2bf(b.w);
            *(uint4*)(As + tid * 8) = *(const uint4*)h;
        }
#pragma unroll
        for (int j = 0; j < 2; j++) {
            const short* gp = dtp_w + (size_t)(col0 + j * 64 + srow) * DTRANK + kt + skch;
            __builtin_amdgcn_global_load_lds(
                (const __attribute__((address_space(1))) void*)gp,
                (__attribute__((address_space(3))) void*)(&Ws[j * 2048 + tid * 8]),
                16, 0, 0);
        }
        __syncthreads();

        bf16x8 af[2], bfr[4];
#pragma unroll
        for (int i = 0; i < 2; i++) {
            const int R = wr * 32 + i * 16 + lrow;
            af[i] = *(const bf16x8*)&As[R * 32 + ((q ^ ((R >> 1) & 3)) * 8)];
        }
#pragma unroll
        for (int j = 0; j < 4; j++) {
            const int R = wc * 64 + j * 16 + lrow;
            bfr[j] = *(const bf16x8*)&Ws[R * 32 + ((q ^ ((R >> 1) & 3)) * 8)];
        }
#pragma unroll
        for (int i = 0; i < 2; i++)
#pragma unroll
            for (int j = 0; j < 4; j++)
                acc[i][j] = __builtin_amdgcn_mfma_f32_16x16x32_bf16(
                    af[i], bfr[j], acc[i][j], 0, 0, 0);
    }

    const int rbase = row0 + wr * 32;
    const int cbase = col0 + wc * 64;
#pragma unroll
    for (int i = 0; i < 2; i++)
#pragma unroll
        for (int j = 0; j < 4; j++) {
            const int gcol = cbase + j * 16 + lrow;
#pragma unroll
            for (int r = 0; r < 4; r++) {
                const int grow = rbase + i * 16 + (lane >> 4) * 4 + r;
                dt_bf[(size_t)grow * DINNER + gcol] =
                    f2bf(softplusf(acc[i][j][r] + dtp_b[gcol]));
            }
        }
}

// ============ Chunked selective scan, conv fused inline ============
// xc[t,e] = silu(cb[e] + sum_k cw[e][k]*xz[t-3+k, e]) via rolling window.
__global__ __launch_bounds__(256) void scan1_g(
    const short* __restrict__ dtb,   // [L, DINNER] bf16
    const short* __restrict__ xzb,   // [L, 2*DINNER] bf16
    const float* __restrict__ cw,    // [DINNER][4]
    const float* __restrict__ cb,    // [DINNER]
    const float* __restrict__ dbl,   // [L, RPROJ] f32
    const float* __restrict__ A_log,
    float* __restrict__ S,           // [NCHUNK][DSTATE][DINNER]
    float* __restrict__ sumdt)       // [NCHUNK][DINNER]
{
    const int e = blockIdx.x * 256 + threadIdx.x;
    const int c = blockIdx.y;
    float a[DSTATE];
#pragma unroll
    for (int n = 0; n < DSTATE; n++) a[n] = -__expf(A_log[(size_t)e * DSTATE + n]);
    float h[DSTATE];
#pragma unroll
    for (int n = 0; n < DSTATE; n++) h[n] = 0.f;
    float sd = 0.f;

    __shared__ float sBC[CHUNK][32];
    for (int i = threadIdx.x; i < CHUNK * 32; i += 256) {
        const int tl = i >> 5, j = i & 31;
        sBC[tl][j] = dbl[(size_t)(c * CHUNK + tl) * RPROJ + DTRANK + j];
    }
    __syncthreads();

    const float4 cwv = *(const float4*)(cw + (size_t)e * 4);
    const float cbv = cb[e];
    const size_t rb = (size_t)c * CHUNK * DINNER + e;
    const size_t xzr = (size_t)c * CHUNK * (2 * DINNER) + e;
    float w1 = 0.f, w2 = 0.f, w3 = 0.f;
    if (c > 0) {
        w1 = bf2f(xzb[xzr - 1 * (2 * DINNER)]);
        w2 = bf2f(xzb[xzr - 2 * (2 * DINNER)]);
        w3 = bf2f(xzb[xzr - 3 * (2 * DINNER)]);
    }
    float w0 = bf2f(xzb[xzr]);
    short dt_c = dtb[rb];
#pragma unroll
    for (int tl = 0; tl < CHUNK; tl++) {
        short dt_n = 0; float xz_n = 0.f;
        if (tl + 1 < CHUNK) {
            dt_n = dtb[rb + (size_t)(tl + 1) * DINNER];
            xz_n = bf2f(xzb[xzr + (size_t)(tl + 1) * (2 * DINNER)]);
        }
        const float xcv = siluf(cbv + cwv.x * w3 + cwv.y * w2 + cwv.z * w1 + cwv.w * w0);
        const float dtv = bf2f(dt_c);
        const float du = dtv * xcv;
        sd += dtv;
#pragma unroll
        for (int n = 0; n < DSTATE; n++) {
            const float dA = __expf(dtv * a[n]);
            h[n] = dA * h[n] + du * sBC[tl][n];
        }
        w3 = w2; w2 = w1; w1 = w0; w0 = xz_n; dt_c = dt_n;
    }
    sumdt[(size_t)c * DINNER + e] = sd;
#pragma unroll
    for (int n = 0; n < DSTATE; n++)
        S[((size_t)c * DSTATE + n) * DINNER + e] = h[n];
}

// pass2: 4-deep software pipeline over the 128-chunk serial dimension
__global__ __launch_bounds__(256) void scan2_g(
    const float* __restrict__ A_log,
    const float* __restrict__ sumdt,
    float* __restrict__ S)
{
    const int idx = blockIdx.x * 256 + threadIdx.x;
    const int e = idx & (DINNER - 1);
    const int n = idx >> 11;
    const float a = -__expf(A_log[(size_t)e * DSTATE + n]);
    const size_t base = (size_t)n * DINNER + e;
    const size_t cstr = (size_t)DSTATE * DINNER;
    float H = 0.f;
    for (int c = 0; c < NCHUNK; c += 4) {
        const float sc0 = S[base + (size_t)(c + 0) * cstr];
        const float sc1 = S[base + (size_t)(c + 1) * cstr];
        const float sc2 = S[base + (size_t)(c + 2) * cstr];
        const float sc3 = S[base + (size_t)(c + 3) * cstr];
        const float sd0 = sumdt[(size_t)(c + 0) * DINNER + e];
        const float sd1 = sumdt[(size_t)(c + 1) * DINNER + e];
        const float sd2 = sumdt[(size_t)(c + 2) * DINNER + e];
        const float sd3 = sumdt[(size_t)(c + 3) * DINNER + e];
        S[base + (size_t)(c + 0) * cstr] = H;
        H = __expf(a * sd0) * H + sc0;
        S[base + (size_t)(c + 1) * cstr] = H;
        H = __expf(a * sd1) * H + sc1;
        S[base + (size_t)(c + 2) * cstr] = H;
        H = __expf(a * sd2) * H + sc2;
        S[base + (size_t)(c + 3) * cstr] = H;
        H = __expf(a * sd3) * H + sc3;
    }
}

__global__ __launch_bounds__(256) void scan3_g(
    const short* __restrict__ dtb,
    const short* __restrict__ xzb,   // xc source (cols 0..2047) + z (cols 2048..)
    const float* __restrict__ cw,
    const float* __restrict__ cb,
    const float* __restrict__ dbl,
    const float* __restrict__ A_log,
    const float* __restrict__ Dp,
    const float* __restrict__ S,
    short* __restrict__ yb)
{
    const int e = blockIdx.x * 256 + threadIdx.x;
    const int c = blockIdx.y;
    float a[DSTATE];
#pragma unroll
    for (int n = 0; n < DSTATE; n++) a[n] = -__expf(A_log[(size_t)e * DSTATE + n]);
    float h[DSTATE];
#pragma unroll
    for (int n = 0; n < DSTATE; n++)
        h[n] = S[((size_t)c * DSTATE + n) * DINNER + e];
    const float dskip = Dp[e];

    __shared__ float sBC[CHUNK][32];
    for (int i = threadIdx.x; i < CHUNK * 32; i += 256) {
        const int tl = i >> 5, j = i & 31;
        sBC[tl][j] = dbl[(size_t)(c * CHUNK + tl) * RPROJ + DTRANK + j];
    }
    __syncthreads();

    const float4 cwv = *(const float4*)(cw + (size_t)e * 4);
    const float cbv = cb[e];
    const size_t rb = (size_t)c * CHUNK * DINNER + e;
    const size_t xzr = (size_t)c * CHUNK * (2 * DINNER) + e;
    const size_t zb = xzr + DINNER;
    float w1 = 0.f, w2 = 0.f, w3 = 0.f;
    if (c > 0) {
        w1 = bf2f(xzb[xzr - 1 * (2 * DINNER)]);
        w2 = bf2f(xzb[xzr - 2 * (2 * DINNER)]);
        w3 = bf2f(xzb[xzr - 3 * (2 * DINNER)]);
    }
    float w0 = bf2f(xzb[xzr]);
    short dt_c = dtb[rb], z_c = xzb[zb];
#pragma unroll
    for (int tl = 0; tl < CHUNK; tl++) {
        short dt_n = 0, z_n = 0; float xz_n = 0.f;
        if (tl + 1 < CHUNK) {
            dt_n = dtb[rb + (size_t)(tl + 1) * DINNER];
            xz_n = bf2f(xzb[xzr + (size_t)(tl + 1) * (2 * DINNER)]);
            z_n = xzb[zb + (size_t)(tl + 1) * (2 * DINNER)];
        }
        const float xcv = siluf(cbv + cwv.x * w3 + cwv.y * w2 + cwv.z * w1 + cwv.w * w0);
        const float dtv = bf2f(dt_c);
        const float du = dtv * xcv;
        float yv = 0.f;
#pragma unroll
        for (int n = 0; n < DSTATE; n++) {
            const float dA = __expf(dtv * a[n]);
            h[n] = dA * h[n] + du * sBC[tl][n];
            yv += h[n] * sBC[tl][16 + n];
        }
        yv = (yv + xcv * dskip) * siluf(bf2f(z_c));
        yb[rb + (size_t)tl * DINNER] = f2bf(yv);
        w3 = w2; w2 = w1; w1 = w0; w0 = xz_n; dt_c = dt_n; z_c = z_n;
    }
}

extern "C" void kernel_launch(void* const* d_in, const int* in_sizes, int n_in,
                              void* d_out, int out_size, void* d_ws, size_t ws_size,
                              hipStream_t stream) {
    const float* x_in   = (const float*)d_in[0];
    const float* ln_w   = (const float*)d_in[1];
    const float* ln_b   = (const float*)d_in[2];
    const float* in_w   = (const float*)d_in[3];
    const float* conv_w = (const float*)d_in[4];
    const float* conv_b = (const float*)d_in[5];
    const float* xp_w   = (const float*)d_in[6];
    const float* dtp_w  = (const float*)d_in[7];
    const float* dtp_b  = (const float*)d_in[8];
    const float* A_log  = (const float*)d_in[9];
    const float* D_skip = (const float*)d_in[10];
    const float* out_w  = (const float*)d_in[11];
    const float* nf_w   = (const float*)d_in[12];
    const float* nf_b   = (const float*)d_in[13];
    float* out = (float*)d_out;

    float* w = (float*)d_ws;
    float* buf_x = w; w += (size_t)LSEQ * DMODEL;              // residual stream (f32)
    float* dbl   = w; w += (size_t)LSEQ * RPROJ;               // x_proj out (f32)
    float* Sbuf  = w; w += (size_t)NCHUNK * DSTATE * DINNER;   // chunk summaries
    float* sumdt = w; w += (size_t)NCHUNK * DINNER;
    // bf16 buffers (sized in float units, 2 shorts per float)
    short* h_bf    = (short*)w; w += (size_t)LSEQ * DMODEL / 2;
    short* xz_bf   = (short*)w; w += (size_t)LSEQ * 2 * DINNER / 2;
    short* dt_bf   = (short*)w; w += (size_t)LSEQ * DINNER / 2;
    short* y_bf    = (short*)w; w += (size_t)LSEQ * DINNER / 2;
    short* in_w_bf  = (short*)w; w += (size_t)2 * (2 * DINNER) * DMODEL / 2;
    short* xp_w_bf  = (short*)w; w += (size_t)2 * RPROJ * DINNER / 2;
    short* dtp_w_bf = (short*)w; w += (size_t)2 * DINNER * DTRANK / 2;
    short* out_w_bf = (short*)w; w += (size_t)2 * DMODEL * DINNER / 2;

    // fused: weight conversion (all layers, 4 tensors) + layer-0 LayerNorm
    {
        const int total = 2 * (2 * DINNER) * DMODEL + 2 * RPROJ * DINNER
                        + 2 * DMODEL * DINNER + 2 * DINNER * DTRANK;  // 13238272
        cvt_ln_kernel<<<dim3(total / (256 * 8)), dim3(256), 0, stream>>>(
            in_w, in_w_bf, xp_w, xp_w_bf, out_w, out_w_bf, dtp_w, dtp_w_bf,
            x_in, ln_w, ln_b, h_bf);
    }

    for (int layer = 0; layer < 2; layer++) {
        const float* resid_src = (layer == 0) ? x_in : buf_x;
        const float* cwl = conv_w + (size_t)layer * DINNER * DCONV;
        const float* cbl = conv_b + (size_t)layer * DINNER;
        // 1. LayerNorm -> bf16 (layer 0 already done in cvt_ln_kernel)
        if (layer > 0)
            ln_g<<<dim3(LSEQ / 4), dim3(256), 0, stream>>>(
                resid_src, ln_w + layer * DMODEL, ln_b + layer * DMODEL,
                nullptr, h_bf);
        // 2. in_proj (MFMA 128x128 BK=64, bf16 out) + fused dbl zero-fill
        gemm_g<4, 4, 3><<<dim3((2 * DINNER) / 128, LSEQ / 128), dim3(256), 0, stream>>>(
            h_bf, DMODEL, in_w_bf + (size_t)layer * 2 * DINNER * DMODEL, DMODEL,
            nullptr, xz_bf, 2 * DINNER, 2 * DINNER, DMODEL, nullptr,
            dbl, (LSEQ * RPROJ) / 4);
        // 3. x_proj with fused conv+silu A-staging (split-K=4, atomicAdd)
        xproj_conv_g<<<dim3(2, LSEQ / 64, XSPLIT), dim3(256), 0, stream>>>(
            xz_bf, cwl, cbl, xp_w_bf + (size_t)layer * RPROJ * DINNER, dbl);
        // 4. dt_proj (64x128, K=64, A from f32 dbl, softplus+bias -> bf16)
        dtproj_g<<<dim3(DINNER / 128, LSEQ / 64), dim3(256), 0, stream>>>(
            dbl, dtp_w_bf + (size_t)layer * DINNER * DTRANK,
            dtp_b + layer * DINNER, dt_bf);
        // 5. chunked selective scan with inline conv (+ skip + z-gate)
        const float* Al = A_log + (size_t)layer * DINNER * DSTATE;
        scan1_g<<<dim3(DINNER / 256, NCHUNK), dim3(256), 0, stream>>>(
            dt_bf, xz_bf, cwl, cbl, dbl, Al, Sbuf, sumdt);
        scan2_g<<<dim3((DINNER * DSTATE) / 256), dim3(256), 0, stream>>>(
            Al, sumdt, Sbuf);
        scan3_g<<<dim3(DINNER / 256, NCHUNK), dim3(256), 0, stream>>>(
            dt_bf, xz_bf, cwl, cbl, dbl, Al, D_skip + layer * DINNER, Sbuf, y_bf);
        // 6. out_proj (MFMA 128x64 BK=64) + residual -> buf_x f32
        gemm_g<4, 2, 2><<<dim3(DMODEL / 64, LSEQ / 128), dim3(256), 0, stream>>>(
            y_bf, DINNER, out_w_bf + (size_t)layer * DMODEL * DINNER, DINNER,
            buf_x, nullptr, DMODEL, DMODEL, DINNER, resid_src,
            nullptr, 0);
    }
    // final LayerNorm -> d_out (f32)
    ln_g<<<dim3(LSEQ / 4), dim3(256), 0, stream>>>(buf_x, nf_w, nf_b, out, nullptr);
}